// Round 12
// baseline (188.859 us; speedup 1.0000x reference)
//
#include <hip/hip_runtime.h>

#define D 128
#define PADV 4     // cnt_v padding (16B per counter)
#define EB 128     // count_e hist chunks
#define EHW 10240  // LDS hist words (u16 pairs) -> supports NE <= 20480

typedef unsigned short ushort_t;
typedef short short8 __attribute__((ext_vector_type(8)));
typedef ushort_t ushort8v __attribute__((ext_vector_type(8)));
typedef float f32x4 __attribute__((ext_vector_type(4)));

static __device__ __forceinline__ unsigned short f2bf(float f){
  unsigned int b = __float_as_uint(f);
  unsigned int r = (b + 0x7FFFu + ((b >> 16) & 1u)) >> 16;
  return (unsigned short)r;
}
static __device__ __forceinline__ float bf2f(unsigned short u){
  return __uint_as_float(((unsigned int)u) << 16);
}

// ---------------- k_hist: count_e via standalone LDS histogram (no fabric atomics)
// chunk b: items [b*per, min((b+1)*per, ni)); local ranks via LDS atomic returns;
// full (packed u16-pair) histogram dumped coalesced to hist_g[b][*].

__global__ __launch_bounds__(256)
void k_hist(const int* __restrict__ hedge_idx, int ni, int ne, int per,
            unsigned* __restrict__ hist_g, int* __restrict__ rank_e){
  __shared__ unsigned hist[EHW];   // 40KB
  int t = threadIdx.x, b = blockIdx.x;
  int i0 = b * per;
  int i1 = i0 + per; if (i1 > ni) i1 = ni;
  int nw = (ne + 1) >> 1;
  for (int k = t; k < nw; k += 256) hist[k] = 0;
  __syncthreads();
  for (int j = i0 + t; j < i1; j += 256){
    int e = hedge_idx[j];
    unsigned old = atomicAdd(&hist[e >> 1], (e & 1) ? 0x10000u : 1u);
    rank_e[j] = (e & 1) ? (int)(old >> 16) : (int)(old & 0xFFFFu);
  }
  __syncthreads();
  unsigned* hg = hist_g + (size_t)b * nw;
  for (int k = t; k < nw; k += 256) hg[k] = hist[k];
}

// ---------------- U1: count_v (atomics) U wprep1 U vconv U colscan_e ----------
// blocks [0,128): Wcf(f32) = Wve@W1, bc = Wve@b1+bve
// blocks [128,128+ns): column-scan of hist_g -> base_g[c][e] + compact cnt_e
// rest: Bresenham mix of vconv (vfeat->bf16) and count_v (random atomics).

__global__ void k_u1(const float* __restrict__ W1, const float* __restrict__ Wve,
                     const float* __restrict__ b1, const float* __restrict__ bve,
                     float* __restrict__ Wcf, float* __restrict__ bc,
                     const float* __restrict__ vfeat, ushort_t* __restrict__ vbf, int nvd,
                     const int* __restrict__ node_idx, const int* __restrict__ hedge_idx,
                     int ni, int ne,
                     const unsigned* __restrict__ hist_g, int* __restrict__ base_g,
                     int* __restrict__ cnt_e,
                     int* __restrict__ cnt_v_pad,
                     int* __restrict__ rank_e, int* __restrict__ rank_v,
                     int eprv, int ns, int vb, int cb){
  int t = threadIdx.x;
  int i = blockIdx.x;
  if (i < 128){
    int r = i;
    if (t < D){
      float acc = 0.f;
      for (int k = 0; k < D; ++k) acc += Wve[r * D + k] * W1[k * D + t];
      Wcf[r * D + t] = acc;
      if (t == 0){
        float s = 0.f;
        for (int k = 0; k < D; ++k) s += Wve[r * D + k] * b1[k];
        bc[r] = s + bve[r];
      }
    }
    return;
  }
  i -= 128;
  if (i < ns){
    if (eprv){
      int nw = (ne + 1) >> 1;
      int w = i * 256 + t;
      if (w < nw){
        int k0 = 2 * w, k1 = 2 * w + 1;
        int run0 = 0, run1 = 0;
        for (int c = 0; c < EB; ++c){
          unsigned h = hist_g[(size_t)c * nw + w];
          base_g[(size_t)c * ne + k0] = run0;
          if (k1 < ne) base_g[(size_t)c * ne + k1] = run1;
          run0 += (int)(h & 0xFFFFu);
          run1 += (int)(h >> 16);
        }
        cnt_e[k0] = run0;
        if (k1 < ne) cnt_e[k1] = run1;
      }
    }
    return;
  }
  i -= ns;
  int total = vb + cb;
  long a0 = (long)i * vb / total, a1 = (long)(i + 1) * vb / total;
  if (a1 != a0){
    // vconv chunk a0: 8192 elems
    size_t base = (size_t)a0 * 8192;
#pragma unroll
    for (int c = 0; c < 4; ++c){
      size_t e8 = base + (size_t)c * 2048 + (size_t)t * 8;
      if (e8 < (size_t)nvd){
        float4 v0 = *(const float4*)&vfeat[e8];
        float4 v1 = *(const float4*)&vfeat[e8 + 4];
        ushort8v h;
        h[0] = f2bf(v0.x); h[1] = f2bf(v0.y); h[2] = f2bf(v0.z); h[3] = f2bf(v0.w);
        h[4] = f2bf(v1.x); h[5] = f2bf(v1.y); h[6] = f2bf(v1.z); h[7] = f2bf(v1.w);
        *(ushort8v*)&vbf[e8] = h;
      }
    }
  } else {
    int idx = (int)(i - a0) * 256 + t;
    if (idx < ni){
      int n = node_idx[idx];
      rank_v[idx] = atomicAdd(&cnt_v_pad[n * PADV], 1);
      if (!eprv)
        rank_e[idx] = atomicAdd(&cnt_e[hedge_idx[idx]], 1);
    }
  }
}

// ---------------- fused scans: partial (strided) + final (inline bsum scan) ----

__device__ __forceinline__ void scan_partial_body(const int* cnt, int n, int stride,
                                                  int* bsum, int b){
  __shared__ int s[256];
  int t = threadIdx.x;
  int base = b * 1024;
  int acc = 0;
  for (int j = t; j < 1024; j += 256){
    int idx = base + j;
    if (idx < n) acc += cnt[(size_t)idx * stride];
  }
  s[t] = acc; __syncthreads();
  for (int o = 128; o > 0; o >>= 1){
    if (t < o) s[t] += s[t + o];
    __syncthreads();
  }
  if (t == 0) bsum[b] = s[0];
}

__global__ void k_scan_partial2(const int* __restrict__ ce, int ne, int* __restrict__ bse,
                                const int* __restrict__ cv, int nv, int* __restrict__ bsv,
                                int nbe){
  if ((int)blockIdx.x < nbe) scan_partial_body(ce, ne, 1, bse, blockIdx.x);
  else                       scan_partial_body(cv, nv, PADV, bsv, blockIdx.x - nbe);
}

// final scan; each block first scans the raw per-block partials (nb <= 256)
__device__ __forceinline__ void scan_final_body(const int* cnt, int n, int stride,
                                                const int* bsum, int nb,
                                                int* off, int* cout, int b){
  __shared__ int s[256];
  int t = threadIdx.x;
  // inline exclusive base from raw partials
  int bv = (t < nb) ? bsum[t] : 0;
  s[t] = bv; __syncthreads();
  for (int o = 1; o < 256; o <<= 1){
    int x = (t >= o) ? s[t - o] : 0;
    __syncthreads();
    s[t] += x;
    __syncthreads();
  }
  int myb = (b == 0) ? 0 : s[b - 1];
  __syncthreads();

  int base = b * 1024 + t * 4;
  int v0 = (base + 0 < n) ? cnt[(size_t)(base + 0) * stride] : 0;
  int v1 = (base + 1 < n) ? cnt[(size_t)(base + 1) * stride] : 0;
  int v2 = (base + 2 < n) ? cnt[(size_t)(base + 2) * stride] : 0;
  int v3 = (base + 3 < n) ? cnt[(size_t)(base + 3) * stride] : 0;
  int lsum = v0 + v1 + v2 + v3;
  s[t] = lsum; __syncthreads();
  for (int o = 1; o < 256; o <<= 1){
    int x = (t >= o) ? s[t - o] : 0;
    __syncthreads();
    s[t] += x;
    __syncthreads();
  }
  int excl = s[t] - lsum + myb;
  if (base + 0 < n){ off[base + 0] = excl;                if (cout) cout[base + 0] = v0; }
  if (base + 1 < n){ off[base + 1] = excl + v0;           if (cout) cout[base + 1] = v1; }
  if (base + 2 < n){ off[base + 2] = excl + v0 + v1;      if (cout) cout[base + 2] = v2; }
  if (base + 3 < n){ off[base + 3] = excl + v0 + v1 + v2; if (cout) cout[base + 3] = v3; }
}

__global__ void k_scan_final2(const int* __restrict__ ce, int ne, const int* __restrict__ bse,
                              int* __restrict__ off_e,
                              const int* __restrict__ cv, int nv, const int* __restrict__ bsv,
                              int* __restrict__ off_v, int* __restrict__ cnt_v,
                              int nbe, int nbv){
  if ((int)blockIdx.x < nbe)
    scan_final_body(ce, ne, 1, bse, nbe, off_e, (int*)nullptr, blockIdx.x);
  else
    scan_final_body(cv, nv, PADV, bsv, nbv, off_v, cnt_v, blockIdx.x - nbe);
}

// ---------------- U2: wprep2 (Wcc = Wev@Wcf, bvec1 = Wev@bc) UNION fill_e --------

__global__ void k_u2(const float* __restrict__ Wev, const float* __restrict__ Wcf,
                     const float* __restrict__ bc,
                     ushort_t* __restrict__ Wcc, float* __restrict__ bvec1,
                     const int* __restrict__ node_idx, const int* __restrict__ hedge_idx,
                     const int* __restrict__ rank_e, int ni, int ne, int per, int eprv,
                     const int* __restrict__ base_g,
                     const int* __restrict__ off_e, int* __restrict__ elist_v){
  int t = threadIdx.x;
  int i = blockIdx.x;
  if (i < 128){
    int r = i;
    if (t < D){
      float acc = 0.f;
      for (int k = 0; k < D; ++k) acc += Wev[r * D + k] * Wcf[k * D + t];
      Wcc[r * D + t] = f2bf(acc);
      if (t == 0){
        float s = 0.f;
        for (int k = 0; k < D; ++k) s += Wev[r * D + k] * bc[k];
        bvec1[r] = s;
      }
    }
  } else {
    int idx = (i - 128) * 256 + t;
    if (idx < ni){
      int e = hedge_idx[idx];
      int pe = off_e[e] + rank_e[idx];
      if (eprv) pe += base_g[(size_t)(idx / per) * ne + e];
      __builtin_nontemporal_store(node_idx[idx], &elist_v[pe]);
    }
  }
}

// ---------------- U3: scatter1 (gather vbf -> agg',wsum') UNION fill_v ----------

__global__ void k_u3(const ushort_t* __restrict__ vbf,
                     const int* __restrict__ off_e, const int* __restrict__ cnt_e,
                     const int* __restrict__ elist,
                     const float* __restrict__ vrw, const float* __restrict__ ers,
                     float* __restrict__ agg, float* __restrict__ wsum,
                     int ne, int sb, int total,
                     const int* __restrict__ node_idx, const int* __restrict__ hedge_idx,
                     const int* __restrict__ rank_v, int ni,
                     const int* __restrict__ off_v, int* __restrict__ vlist_e){
  int i = blockIdx.x;
  long a0 = (long)i * sb / total, a1 = (long)(i + 1) * sb / total;
  if (a1 != a0){
    int tid = threadIdx.x;
    int seg = (int)a0 * 16 + (tid >> 4);
    if (seg >= ne) return;
    int l16 = tid & 15;
    int s = off_e[seg], n = cnt_e[seg];
    float inv = 1.0f / ers[seg];

    float acc[8];
#pragma unroll
    for (int c = 0; c < 8; ++c) acc[c] = 0.f;
    float wa = 0.f;

    int j = 0;
    for (; j + 2 <= n; j += 2){
      int r0 = elist[s + j];
      int r1 = elist[s + j + 1];
      float w0 = vrw[r0];
      float w1 = vrw[r1];
      ushort8v x0 = *(const ushort8v*)&vbf[(size_t)r0 * D + l16 * 8];
      ushort8v x1 = *(const ushort8v*)&vbf[(size_t)r1 * D + l16 * 8];
      wa += w0 + w1;
#pragma unroll
      for (int c = 0; c < 8; ++c) acc[c] += w0 * bf2f(x0[c]) + w1 * bf2f(x1[c]);
    }
    if (j < n){
      int r0 = elist[s + j];
      float w0 = vrw[r0];
      ushort8v x0 = *(const ushort8v*)&vbf[(size_t)r0 * D + l16 * 8];
      wa += w0;
#pragma unroll
      for (int c = 0; c < 8; ++c) acc[c] += w0 * bf2f(x0[c]);
    }

    float* dp = &agg[(size_t)seg * D + l16 * 8];
    float4 o0, o1;
    o0.x = acc[0] * inv; o0.y = acc[1] * inv; o0.z = acc[2] * inv; o0.w = acc[3] * inv;
    o1.x = acc[4] * inv; o1.y = acc[5] * inv; o1.z = acc[6] * inv; o1.w = acc[7] * inv;
    *(float4*)dp = o0;
    *(float4*)(dp + 4) = o1;
    if (l16 == 0) wsum[seg] = wa * inv;
  } else {
    int idx = (int)(i - a0) * 256 + threadIdx.x;
    if (idx < ni){
      int pv = off_v[node_idx[idx]] + rank_v[idx];
      __builtin_nontemporal_store(hedge_idx[idx], &vlist_e[pv]);
    }
  }
}

// ---------------- MFMA GEMM with row-scale bias ----------------
// Wh_e(bf16)[M x 128] = agg(f32)[M x 128] @ Wcc(bf16).T + wsum[row]*bvec1 + bev.

__global__ __launch_bounds__(256, 2)
void k_gemm_rs(const float* __restrict__ A, const ushort_t* __restrict__ Wb,
               const float* __restrict__ wsum, const float* __restrict__ bvec1,
               const float* __restrict__ bev, ushort_t* __restrict__ out, int M){
  __shared__ ushort_t Al[64 * D];

  const int t = threadIdx.x;
  const int w = t >> 6;
  const int l = t & 63;
  const int l15 = l & 15;
  const int lh = l >> 4;

  short8 breg[4][8];
#pragma unroll
  for (int kc = 0; kc < 4; ++kc)
#pragma unroll
    for (int n0 = 0; n0 < 8; ++n0)
      breg[kc][n0] = *(const short8*)&Wb[(n0 * 16 + l15) * D + kc * 32 + lh * 8];

  float bv1_r[8], bev_r[8];
#pragma unroll
  for (int n0 = 0; n0 < 8; ++n0){
    bv1_r[n0] = bvec1[n0 * 16 + l15];
    bev_r[n0] = bev[n0 * 16 + l15];
  }

  const int r_st = t >> 2;
  const int q_st = t & 3;
  const int ntile = (M + 63) >> 6;

  for (int tile = blockIdx.x; tile < ntile; tile += gridDim.x){
    const int row0 = tile << 6;
    __syncthreads();
    {
      int r = row0 + r_st;
      ushort8v h[4];
      if (r < M){
        const float4* src = (const float4*)&A[(size_t)r * D + q_st * 32];
        float4 v[8];
#pragma unroll
        for (int ii = 0; ii < 8; ++ii) v[ii] = src[ii];
#pragma unroll
        for (int c = 0; c < 4; ++c){
          h[c][0] = f2bf(v[2*c].x);   h[c][1] = f2bf(v[2*c].y);
          h[c][2] = f2bf(v[2*c].z);   h[c][3] = f2bf(v[2*c].w);
          h[c][4] = f2bf(v[2*c+1].x); h[c][5] = f2bf(v[2*c+1].y);
          h[c][6] = f2bf(v[2*c+1].z); h[c][7] = f2bf(v[2*c+1].w);
        }
      } else {
#pragma unroll
        for (int c = 0; c < 4; ++c) h[c] = (ushort8v){0,0,0,0,0,0,0,0};
      }
#pragma unroll
      for (int c = 0; c < 4; ++c){
        int col = q_st * 32 + c * 8;
        int swz = col ^ ((r_st & 7) << 3);
        *(ushort8v*)&Al[r_st * D + swz] = h[c];
      }
    }
    __syncthreads();

    f32x4 acc[8];
#pragma unroll
    for (int n0 = 0; n0 < 8; ++n0) acc[n0] = (f32x4){0.f, 0.f, 0.f, 0.f};

#pragma unroll
    for (int kc = 0; kc < 4; ++kc){
      const int arow = w * 16 + l15;
      const int acol = (kc * 32 + lh * 8) ^ ((l15 & 7) << 3);
      short8 a = *(const short8*)&Al[arow * D + acol];
#pragma unroll
      for (int n0 = 0; n0 < 8; ++n0)
        acc[n0] = __builtin_amdgcn_mfma_f32_16x16x32_bf16(a, breg[kc][n0], acc[n0], 0, 0, 0);
    }

    // C/D layout: col = lane&15, row = (lane>>4)*4 + reg
    const int rbase = row0 + w * 16 + lh * 4;
    float w4[4];
#pragma unroll
    for (int rg = 0; rg < 4; ++rg)
      w4[rg] = (rbase + rg < M) ? wsum[rbase + rg] : 0.f;
#pragma unroll
    for (int n0 = 0; n0 < 8; ++n0){
      const int colo = n0 * 16 + l15;
#pragma unroll
      for (int rg = 0; rg < 4; ++rg){
        int row = rbase + rg;
        if (row < M)
          out[(size_t)row * D + colo] = f2bf(acc[n0][rg] + w4[rg] * bv1_r[n0] + bev_r[n0]);
      }
    }
  }
}

// ---------------- scatter2: group-per-segment gather Wh_e -> d_out (f32) --------

__global__ void k_scatter2(const ushort_t* __restrict__ src,
                           const int* __restrict__ off, const int* __restrict__ cnt,
                           const int* __restrict__ list,
                           const float* __restrict__ wnum, const float* __restrict__ dsum,
                           float* __restrict__ dst, int nseg){
  int tid = threadIdx.x;
  int seg = blockIdx.x * 16 + (tid >> 4);
  if (seg >= nseg) return;
  int l16 = tid & 15;
  int s = off[seg], n = cnt[seg];
  float inv = 1.0f / dsum[seg];

  float acc[8];
#pragma unroll
  for (int c = 0; c < 8; ++c) acc[c] = 0.f;

  int j = 0;
  for (; j + 2 <= n; j += 2){
    int r0 = list[s + j];
    int r1 = list[s + j + 1];
    float w0 = wnum[r0] * inv;
    float w1 = wnum[r1] * inv;
    ushort8v x0 = *(const ushort8v*)&src[(size_t)r0 * D + l16 * 8];
    ushort8v x1 = *(const ushort8v*)&src[(size_t)r1 * D + l16 * 8];
#pragma unroll
    for (int c = 0; c < 8; ++c) acc[c] += w0 * bf2f(x0[c]) + w1 * bf2f(x1[c]);
  }
  if (j < n){
    int r0 = list[s + j];
    float w0 = wnum[r0] * inv;
    ushort8v x0 = *(const ushort8v*)&src[(size_t)r0 * D + l16 * 8];
#pragma unroll
    for (int c = 0; c < 8; ++c) acc[c] += w0 * bf2f(x0[c]);
  }

  float* dp = &dst[(size_t)seg * D + l16 * 8];
  float4 o0, o1;
  o0.x = acc[0]; o0.y = acc[1]; o0.z = acc[2]; o0.w = acc[3];
  o1.x = acc[4]; o1.y = acc[5]; o1.z = acc[6]; o1.w = acc[7];
  *(float4*)dp = o0;
  *(float4*)(dp + 4) = o1;
}

// ---------------- host ----------------

static inline int cdiv(int a, int b){ return (a + b - 1) / b; }

extern "C" void kernel_launch(void* const* d_in, const int* in_sizes, int n_in,
                              void* d_out, int out_size, void* d_ws, size_t ws_size,
                              hipStream_t stream){
  const float* vfeat        = (const float*)d_in[0];
  const float* v_reg_weight = (const float*)d_in[2];
  const float* v_reg_sum    = (const float*)d_in[3];
  const float* e_reg_weight = (const float*)d_in[4];
  const float* e_reg_sum    = (const float*)d_in[5];
  const int*   node_idx     = (const int*)d_in[6];
  const int*   hedge_idx    = (const int*)d_in[7];
  const float* W1  = (const float*)d_in[8];
  const float* b1  = (const float*)d_in[9];
  const float* Wve = (const float*)d_in[10];
  const float* bve = (const float*)d_in[11];
  const float* Wev = (const float*)d_in[12];
  const float* bev = (const float*)d_in[13];

  const int NV = in_sizes[2];
  const int NE = in_sizes[4];
  const int NI = in_sizes[6];
  const int NVD = NV * D;

  char* p = (char*)d_ws;
  auto alloc = [&](size_t nbytes) -> void* {
    void* q = (void*)p;
    p += (nbytes + 255) & ~(size_t)255;
    return q;
  };

  char* zstart = p;
  int* cnt_e     = (int*)alloc(((size_t)NE + 2) * 4);
  int* cnt_v_pad = (int*)alloc((size_t)NV * PADV * 4);
  size_t zbytes = (size_t)(p - zstart);

  unsigned* hist_g = (unsigned*)alloc((size_t)EB * EHW * 4);  // 5.2MB
  int* base_g = (int*)alloc((size_t)EB * NE * 4);             // 10.2MB
  int* cnt_v  = (int*)alloc((size_t)NV * 4);
  int* off_e  = (int*)alloc((size_t)NE * 4);
  int* off_v  = (int*)alloc((size_t)NV * 4);
  int* bsum_e = (int*)alloc(1024 * 4);
  int* bsum_v = (int*)alloc(1024 * 4);
  int* rank_e = (int*)alloc((size_t)NI * 4);
  int* rank_v = (int*)alloc((size_t)NI * 4);
  int* elist_v = (int*)alloc((size_t)NI * 4);   // per edge-slot: vertex id
  int* vlist_e = (int*)alloc((size_t)NI * 4);   // per vertex-slot: edge id
  float* Wcf     = (float*)alloc((size_t)D * D * 4);   // Wve@W1 (f32)
  float* bc      = (float*)alloc((size_t)D * 4);
  ushort_t* Wcc  = (ushort_t*)alloc((size_t)D * D * 2); // Wev@Wcf (bf16)
  float* bvec1   = (float*)alloc((size_t)D * 4);        // Wev@bc
  ushort_t* Wh_e = (ushort_t*)alloc((size_t)NE * D * 2);

  // d_out doubles as scratch; fully overwritten by scatter2 at the end.
  ushort_t* vbf  = (ushort_t*)d_out;                       // [NV*D] bf16 = 25.6MB
  float*    agg  = (float*)((char*)d_out + (size_t)NVD * 2);          // [NE*D] f32
  float*    wsum = (float*)((char*)d_out + (size_t)NVD * 2 + (size_t)NE * D * 4);

  hipMemsetAsync(zstart, 0, zbytes, stream);

  int eprv = (NE <= 2 * EHW) ? 1 : 0;
  int per = cdiv(NI, EB);
  if (eprv)
    k_hist<<<EB, 256, 0, stream>>>(hedge_idx, NI, NE, per, hist_g, rank_e);

  // U1: wprep1 + colscan_e + Bresenham{vconv, count_v}
  int cb = cdiv(NI, 256);
  int vb = cdiv(NVD, 8192);
  int ns = cdiv((NE + 1) >> 1, 256);
  k_u1<<<128 + ns + vb + cb, 256, 0, stream>>>(W1, Wve, b1, bve, Wcf, bc,
                                               vfeat, vbf, NVD,
                                               node_idx, hedge_idx, NI, NE,
                                               hist_g, base_g, cnt_e,
                                               cnt_v_pad, rank_e, rank_v,
                                               eprv, ns, vb, cb);

  // fused scans (e compact stride-1 + v padded); final includes bsum scan
  int nbe = cdiv(NE, 1024), nbv = cdiv(NV, 1024);
  k_scan_partial2<<<nbe + nbv, 256, 0, stream>>>(cnt_e, NE, bsum_e,
                                                 cnt_v_pad, NV, bsum_v, nbe);
  k_scan_final2<<<nbe + nbv, 256, 0, stream>>>(cnt_e, NE, bsum_e, off_e,
                                               cnt_v_pad, NV, bsum_v, off_v, cnt_v,
                                               nbe, nbv);

  // U2: wprep2 (Wcc, bvec1) + fill_e (chunk-base + local rank)
  k_u2<<<128 + cb, 256, 0, stream>>>(Wev, Wcf, bc, Wcc, bvec1,
                                     node_idx, hedge_idx, rank_e, NI, NE, per, eprv,
                                     base_g, off_e, elist_v);

  // U3: Bresenham{scatter1 -> agg/wsum, fill_v}
  int sb = cdiv(NE, 16);
  int u3_total = sb + cb;
  k_u3<<<u3_total, 256, 0, stream>>>(vbf, off_e, cnt_e, elist_v,
                                     v_reg_weight, e_reg_sum,
                                     agg, wsum, NE, sb, u3_total,
                                     node_idx, hedge_idx, rank_v, NI,
                                     off_v, vlist_e);

  // Wh_e = agg @ Wcc.T + wsum*bvec1 + bev  (bf16 out)
  k_gemm_rs<<<cdiv(NE, 64), 256, 0, stream>>>(agg, Wcc, wsum, bvec1, bev, Wh_e, NE);

  // d_out[v] = (1/vrs[v]) * sum erw[e]*Wh_e[e]
  k_scatter2<<<cdiv(NV, 16), 256, 0, stream>>>(Wh_e, off_v, cnt_v, vlist_e,
                                               e_reg_weight, v_reg_sum,
                                               (float*)d_out, NV);
}

// Round 13
// 165.466 us; speedup vs baseline: 1.1414x; 1.1414x over previous
//
#include <hip/hip_runtime.h>

#define D 128
#define PADE 16   // cnt_e line-padding (64B per counter)
#define PADV 4    // cnt_v padding (16B per counter)

typedef unsigned short ushort_t;
typedef short short8 __attribute__((ext_vector_type(8)));
typedef ushort_t ushort8v __attribute__((ext_vector_type(8)));
typedef float f32x4 __attribute__((ext_vector_type(4)));

static __device__ __forceinline__ unsigned short f2bf(float f){
  unsigned int b = __float_as_uint(f);
  unsigned int r = (b + 0x7FFFu + ((b >> 16) & 1u)) >> 16;
  return (unsigned short)r;
}
static __device__ __forceinline__ float bf2f(unsigned short u){
  return __uint_as_float(((unsigned int)u) << 16);
}

// ---------------- U1: counts (padded atomics) UNION wprep1 UNION vconv ----------
// blocks [0,128): Wcf(f32) = Wve@W1, bc = Wve@b1+bve
// rest: Bresenham mix of vconv (vfeat->bf16) and count_e+count_v.

__global__ void k_u1(const float* __restrict__ W1, const float* __restrict__ Wve,
                     const float* __restrict__ b1, const float* __restrict__ bve,
                     float* __restrict__ Wcf, float* __restrict__ bc,
                     const float* __restrict__ vfeat, ushort_t* __restrict__ vbf, int nvd,
                     const int* __restrict__ node_idx, const int* __restrict__ hedge_idx, int ni,
                     int* __restrict__ cnt_e_pad, int* __restrict__ cnt_v_pad,
                     int* __restrict__ rank_e, int* __restrict__ rank_v,
                     int vb, int cb){
  int t = threadIdx.x;
  int i = blockIdx.x;
  if (i < 128){
    int r = i;
    if (t < D){
      float acc = 0.f;
      for (int k = 0; k < D; ++k) acc += Wve[r * D + k] * W1[k * D + t];
      Wcf[r * D + t] = acc;
      if (t == 0){
        float s = 0.f;
        for (int k = 0; k < D; ++k) s += Wve[r * D + k] * b1[k];
        bc[r] = s + bve[r];
      }
    }
    return;
  }
  int j = i - 128;
  int total = vb + cb;
  long a0 = (long)j * vb / total, a1 = (long)(j + 1) * vb / total;
  if (a1 != a0){
    // vconv chunk a0: 8192 elems
    size_t base = (size_t)a0 * 8192;
#pragma unroll
    for (int c = 0; c < 4; ++c){
      size_t e8 = base + (size_t)c * 2048 + (size_t)t * 8;
      if (e8 < (size_t)nvd){
        float4 v0 = *(const float4*)&vfeat[e8];
        float4 v1 = *(const float4*)&vfeat[e8 + 4];
        ushort8v h;
        h[0] = f2bf(v0.x); h[1] = f2bf(v0.y); h[2] = f2bf(v0.z); h[3] = f2bf(v0.w);
        h[4] = f2bf(v1.x); h[5] = f2bf(v1.y); h[6] = f2bf(v1.z); h[7] = f2bf(v1.w);
        *(ushort8v*)&vbf[e8] = h;
      }
    }
  } else {
    int idx = (int)(j - a0) * 256 + t;
    if (idx < ni){
      int n = node_idx[idx], h = hedge_idx[idx];
      rank_e[idx] = atomicAdd(&cnt_e_pad[h * PADE], 1);
      rank_v[idx] = atomicAdd(&cnt_v_pad[n * PADV], 1);
    }
  }
}

// ---------------- fused scans: partial (strided) + final (inline bsum scan) ----

__device__ __forceinline__ void scan_partial_body(const int* cnt, int n, int stride,
                                                  int* bsum, int b){
  __shared__ int s[256];
  int t = threadIdx.x;
  int base = b * 1024;
  int acc = 0;
  for (int j = t; j < 1024; j += 256){
    int idx = base + j;
    if (idx < n) acc += cnt[(size_t)idx * stride];
  }
  s[t] = acc; __syncthreads();
  for (int o = 128; o > 0; o >>= 1){
    if (t < o) s[t] += s[t + o];
    __syncthreads();
  }
  if (t == 0) bsum[b] = s[0];
}

__global__ void k_scan_partial2(const int* __restrict__ ce, int ne, int* __restrict__ bse,
                                const int* __restrict__ cv, int nv, int* __restrict__ bsv,
                                int nbe){
  if ((int)blockIdx.x < nbe) scan_partial_body(ce, ne, PADE, bse, blockIdx.x);
  else                       scan_partial_body(cv, nv, PADV, bsv, blockIdx.x - nbe);
}

// final scan; each block first scans the raw per-block partials (nb <= 256)
__device__ __forceinline__ void scan_final_body(const int* cnt, int n, int stride,
                                                const int* bsum, int nb,
                                                int* off, int* cout, int b){
  __shared__ int s[256];
  int t = threadIdx.x;
  int bv = (t < nb) ? bsum[t] : 0;
  s[t] = bv; __syncthreads();
  for (int o = 1; o < 256; o <<= 1){
    int x = (t >= o) ? s[t - o] : 0;
    __syncthreads();
    s[t] += x;
    __syncthreads();
  }
  int myb = (b == 0) ? 0 : s[b - 1];
  __syncthreads();

  int base = b * 1024 + t * 4;
  int v0 = (base + 0 < n) ? cnt[(size_t)(base + 0) * stride] : 0;
  int v1 = (base + 1 < n) ? cnt[(size_t)(base + 1) * stride] : 0;
  int v2 = (base + 2 < n) ? cnt[(size_t)(base + 2) * stride] : 0;
  int v3 = (base + 3 < n) ? cnt[(size_t)(base + 3) * stride] : 0;
  int lsum = v0 + v1 + v2 + v3;
  s[t] = lsum; __syncthreads();
  for (int o = 1; o < 256; o <<= 1){
    int x = (t >= o) ? s[t - o] : 0;
    __syncthreads();
    s[t] += x;
    __syncthreads();
  }
  int excl = s[t] - lsum + myb;
  if (base + 0 < n){ off[base + 0] = excl;                cout[base + 0] = v0; }
  if (base + 1 < n){ off[base + 1] = excl + v0;           cout[base + 1] = v1; }
  if (base + 2 < n){ off[base + 2] = excl + v0 + v1;      cout[base + 2] = v2; }
  if (base + 3 < n){ off[base + 3] = excl + v0 + v1 + v2; cout[base + 3] = v3; }
}

__global__ void k_scan_final2(const int* __restrict__ ce, int ne, const int* __restrict__ bse,
                              int* __restrict__ off_e, int* __restrict__ cnt_e,
                              const int* __restrict__ cv, int nv, const int* __restrict__ bsv,
                              int* __restrict__ off_v, int* __restrict__ cnt_v,
                              int nbe, int nbv){
  if ((int)blockIdx.x < nbe)
    scan_final_body(ce, ne, PADE, bse, nbe, off_e, cnt_e, blockIdx.x);
  else
    scan_final_body(cv, nv, PADV, bsv, nbv, off_v, cnt_v, blockIdx.x - nbe);
}

// ---------------- U2: wprep2 (Wcc = Wev@Wcf, bvec1 = Wev@bc) UNION fill_e --------
// fill_e uses PLAIN stores: target region (NI*4 = 2.4MB) is L2-resident; lines
// merge in L2 and write back byte-masked at kernel end (vs NT full-line dirties).

__global__ void k_u2(const float* __restrict__ Wev, const float* __restrict__ Wcf,
                     const float* __restrict__ bc,
                     ushort_t* __restrict__ Wcc, float* __restrict__ bvec1,
                     const int* __restrict__ node_idx, const int* __restrict__ hedge_idx,
                     const int* __restrict__ rank_e, int ni,
                     const int* __restrict__ off_e, int* __restrict__ elist_v){
  int t = threadIdx.x;
  int i = blockIdx.x;
  if (i < 128){
    int r = i;
    if (t < D){
      float acc = 0.f;
      for (int k = 0; k < D; ++k) acc += Wev[r * D + k] * Wcf[k * D + t];
      Wcc[r * D + t] = f2bf(acc);
      if (t == 0){
        float s = 0.f;
        for (int k = 0; k < D; ++k) s += Wev[r * D + k] * bc[k];
        bvec1[r] = s;
      }
    }
  } else {
    int idx = (i - 128) * 256 + t;
    if (idx < ni){
      int pe = off_e[hedge_idx[idx]] + rank_e[idx];
      elist_v[pe] = node_idx[idx];          // plain store (L2 write-combine)
    }
  }
}

// ---------------- U3: scatter1 (gather vbf -> agg',wsum') UNION fill_v ----------

__global__ void k_u3(const ushort_t* __restrict__ vbf,
                     const int* __restrict__ off_e, const int* __restrict__ cnt_e,
                     const int* __restrict__ elist,
                     const float* __restrict__ vrw, const float* __restrict__ ers,
                     float* __restrict__ agg, float* __restrict__ wsum,
                     int ne, int sb, int total,
                     const int* __restrict__ node_idx, const int* __restrict__ hedge_idx,
                     const int* __restrict__ rank_v, int ni,
                     const int* __restrict__ off_v, int* __restrict__ vlist_e){
  int i = blockIdx.x;
  long a0 = (long)i * sb / total, a1 = (long)(i + 1) * sb / total;
  if (a1 != a0){
    int tid = threadIdx.x;
    int seg = (int)a0 * 16 + (tid >> 4);
    if (seg >= ne) return;
    int l16 = tid & 15;
    int s = off_e[seg], n = cnt_e[seg];
    float inv = 1.0f / ers[seg];

    float acc[8];
#pragma unroll
    for (int c = 0; c < 8; ++c) acc[c] = 0.f;
    float wa = 0.f;

    int j = 0;
    for (; j + 2 <= n; j += 2){
      int r0 = elist[s + j];
      int r1 = elist[s + j + 1];
      float w0 = vrw[r0];
      float w1 = vrw[r1];
      ushort8v x0 = *(const ushort8v*)&vbf[(size_t)r0 * D + l16 * 8];
      ushort8v x1 = *(const ushort8v*)&vbf[(size_t)r1 * D + l16 * 8];
      wa += w0 + w1;
#pragma unroll
      for (int c = 0; c < 8; ++c) acc[c] += w0 * bf2f(x0[c]) + w1 * bf2f(x1[c]);
    }
    if (j < n){
      int r0 = elist[s + j];
      float w0 = vrw[r0];
      ushort8v x0 = *(const ushort8v*)&vbf[(size_t)r0 * D + l16 * 8];
      wa += w0;
#pragma unroll
      for (int c = 0; c < 8; ++c) acc[c] += w0 * bf2f(x0[c]);
    }

    float* dp = &agg[(size_t)seg * D + l16 * 8];
    float4 o0, o1;
    o0.x = acc[0] * inv; o0.y = acc[1] * inv; o0.z = acc[2] * inv; o0.w = acc[3] * inv;
    o1.x = acc[4] * inv; o1.y = acc[5] * inv; o1.z = acc[6] * inv; o1.w = acc[7] * inv;
    *(float4*)dp = o0;
    *(float4*)(dp + 4) = o1;
    if (l16 == 0) wsum[seg] = wa * inv;
  } else {
    int idx = (int)(i - a0) * 256 + threadIdx.x;
    if (idx < ni){
      int pv = off_v[node_idx[idx]] + rank_v[idx];
      vlist_e[pv] = hedge_idx[idx];         // plain store (L2 write-combine)
    }
  }
}

// ---------------- MFMA GEMM with row-scale bias ----------------
// Wh_e(bf16)[M x 128] = agg(f32)[M x 128] @ Wcc(bf16).T + wsum[row]*bvec1 + bev.

__global__ __launch_bounds__(256, 2)
void k_gemm_rs(const float* __restrict__ A, const ushort_t* __restrict__ Wb,
               const float* __restrict__ wsum, const float* __restrict__ bvec1,
               const float* __restrict__ bev, ushort_t* __restrict__ out, int M){
  __shared__ ushort_t Al[64 * D];

  const int t = threadIdx.x;
  const int w = t >> 6;
  const int l = t & 63;
  const int l15 = l & 15;
  const int lh = l >> 4;

  short8 breg[4][8];
#pragma unroll
  for (int kc = 0; kc < 4; ++kc)
#pragma unroll
    for (int n0 = 0; n0 < 8; ++n0)
      breg[kc][n0] = *(const short8*)&Wb[(n0 * 16 + l15) * D + kc * 32 + lh * 8];

  float bv1_r[8], bev_r[8];
#pragma unroll
  for (int n0 = 0; n0 < 8; ++n0){
    bv1_r[n0] = bvec1[n0 * 16 + l15];
    bev_r[n0] = bev[n0 * 16 + l15];
  }

  const int r_st = t >> 2;
  const int q_st = t & 3;
  const int ntile = (M + 63) >> 6;

  for (int tile = blockIdx.x; tile < ntile; tile += gridDim.x){
    const int row0 = tile << 6;
    __syncthreads();
    {
      int r = row0 + r_st;
      ushort8v h[4];
      if (r < M){
        const float4* src = (const float4*)&A[(size_t)r * D + q_st * 32];
        float4 v[8];
#pragma unroll
        for (int ii = 0; ii < 8; ++ii) v[ii] = src[ii];
#pragma unroll
        for (int c = 0; c < 4; ++c){
          h[c][0] = f2bf(v[2*c].x);   h[c][1] = f2bf(v[2*c].y);
          h[c][2] = f2bf(v[2*c].z);   h[c][3] = f2bf(v[2*c].w);
          h[c][4] = f2bf(v[2*c+1].x); h[c][5] = f2bf(v[2*c+1].y);
          h[c][6] = f2bf(v[2*c+1].z); h[c][7] = f2bf(v[2*c+1].w);
        }
      } else {
#pragma unroll
        for (int c = 0; c < 4; ++c) h[c] = (ushort8v){0,0,0,0,0,0,0,0};
      }
#pragma unroll
      for (int c = 0; c < 4; ++c){
        int col = q_st * 32 + c * 8;
        int swz = col ^ ((r_st & 7) << 3);
        *(ushort8v*)&Al[r_st * D + swz] = h[c];
      }
    }
    __syncthreads();

    f32x4 acc[8];
#pragma unroll
    for (int n0 = 0; n0 < 8; ++n0) acc[n0] = (f32x4){0.f, 0.f, 0.f, 0.f};

#pragma unroll
    for (int kc = 0; kc < 4; ++kc){
      const int arow = w * 16 + l15;
      const int acol = (kc * 32 + lh * 8) ^ ((l15 & 7) << 3);
      short8 a = *(const short8*)&Al[arow * D + acol];
#pragma unroll
      for (int n0 = 0; n0 < 8; ++n0)
        acc[n0] = __builtin_amdgcn_mfma_f32_16x16x32_bf16(a, breg[kc][n0], acc[n0], 0, 0, 0);
    }

    // C/D layout: col = lane&15, row = (lane>>4)*4 + reg
    const int rbase = row0 + w * 16 + lh * 4;
    float w4[4];
#pragma unroll
    for (int rg = 0; rg < 4; ++rg)
      w4[rg] = (rbase + rg < M) ? wsum[rbase + rg] : 0.f;
#pragma unroll
    for (int n0 = 0; n0 < 8; ++n0){
      const int colo = n0 * 16 + l15;
#pragma unroll
      for (int rg = 0; rg < 4; ++rg){
        int row = rbase + rg;
        if (row < M)
          out[(size_t)row * D + colo] = f2bf(acc[n0][rg] + w4[rg] * bv1_r[n0] + bev_r[n0]);
      }
    }
  }
}

// ---------------- scatter2: group-per-segment gather Wh_e -> d_out (f32) --------

__global__ void k_scatter2(const ushort_t* __restrict__ src,
                           const int* __restrict__ off, const int* __restrict__ cnt,
                           const int* __restrict__ list,
                           const float* __restrict__ wnum, const float* __restrict__ dsum,
                           float* __restrict__ dst, int nseg){
  int tid = threadIdx.x;
  int seg = blockIdx.x * 16 + (tid >> 4);
  if (seg >= nseg) return;
  int l16 = tid & 15;
  int s = off[seg], n = cnt[seg];
  float inv = 1.0f / dsum[seg];

  float acc[8];
#pragma unroll
  for (int c = 0; c < 8; ++c) acc[c] = 0.f;

  int j = 0;
  for (; j + 2 <= n; j += 2){
    int r0 = list[s + j];
    int r1 = list[s + j + 1];
    float w0 = wnum[r0] * inv;
    float w1 = wnum[r1] * inv;
    ushort8v x0 = *(const ushort8v*)&src[(size_t)r0 * D + l16 * 8];
    ushort8v x1 = *(const ushort8v*)&src[(size_t)r1 * D + l16 * 8];
#pragma unroll
    for (int c = 0; c < 8; ++c) acc[c] += w0 * bf2f(x0[c]) + w1 * bf2f(x1[c]);
  }
  if (j < n){
    int r0 = list[s + j];
    float w0 = wnum[r0] * inv;
    ushort8v x0 = *(const ushort8v*)&src[(size_t)r0 * D + l16 * 8];
#pragma unroll
    for (int c = 0; c < 8; ++c) acc[c] += w0 * bf2f(x0[c]);
  }

  float* dp = &dst[(size_t)seg * D + l16 * 8];
  float4 o0, o1;
  o0.x = acc[0]; o0.y = acc[1]; o0.z = acc[2]; o0.w = acc[3];
  o1.x = acc[4]; o1.y = acc[5]; o1.z = acc[6]; o1.w = acc[7];
  *(float4*)dp = o0;
  *(float4*)(dp + 4) = o1;
}

// ---------------- host ----------------

static inline int cdiv(int a, int b){ return (a + b - 1) / b; }

extern "C" void kernel_launch(void* const* d_in, const int* in_sizes, int n_in,
                              void* d_out, int out_size, void* d_ws, size_t ws_size,
                              hipStream_t stream){
  const float* vfeat        = (const float*)d_in[0];
  const float* v_reg_weight = (const float*)d_in[2];
  const float* v_reg_sum    = (const float*)d_in[3];
  const float* e_reg_weight = (const float*)d_in[4];
  const float* e_reg_sum    = (const float*)d_in[5];
  const int*   node_idx     = (const int*)d_in[6];
  const int*   hedge_idx    = (const int*)d_in[7];
  const float* W1  = (const float*)d_in[8];
  const float* b1  = (const float*)d_in[9];
  const float* Wve = (const float*)d_in[10];
  const float* bve = (const float*)d_in[11];
  const float* Wev = (const float*)d_in[12];
  const float* bev = (const float*)d_in[13];

  const int NV = in_sizes[2];
  const int NE = in_sizes[4];
  const int NI = in_sizes[6];
  const int NVD = NV * D;

  char* p = (char*)d_ws;
  auto alloc = [&](size_t nbytes) -> void* {
    void* q = (void*)p;
    p += (nbytes + 255) & ~(size_t)255;
    return q;
  };

  char* zstart = p;
  int* cnt_e_pad = (int*)alloc((size_t)NE * PADE * 4);
  int* cnt_v_pad = (int*)alloc((size_t)NV * PADV * 4);
  size_t zbytes = (size_t)(p - zstart);

  int* cnt_e  = (int*)alloc((size_t)NE * 4);
  int* cnt_v  = (int*)alloc((size_t)NV * 4);
  int* off_e  = (int*)alloc((size_t)NE * 4);
  int* off_v  = (int*)alloc((size_t)NV * 4);
  int* bsum_e = (int*)alloc(1024 * 4);
  int* bsum_v = (int*)alloc(1024 * 4);
  int* rank_e = (int*)alloc((size_t)NI * 4);
  int* rank_v = (int*)alloc((size_t)NI * 4);
  int* elist_v = (int*)alloc((size_t)NI * 4);   // per edge-slot: vertex id
  int* vlist_e = (int*)alloc((size_t)NI * 4);   // per vertex-slot: edge id
  float* Wcf     = (float*)alloc((size_t)D * D * 4);   // Wve@W1 (f32)
  float* bc      = (float*)alloc((size_t)D * 4);
  ushort_t* Wcc  = (ushort_t*)alloc((size_t)D * D * 2); // Wev@Wcf (bf16)
  float* bvec1   = (float*)alloc((size_t)D * 4);        // Wev@bc
  ushort_t* Wh_e = (ushort_t*)alloc((size_t)NE * D * 2);

  // d_out doubles as scratch; fully overwritten by scatter2 at the end.
  ushort_t* vbf  = (ushort_t*)d_out;                       // [NV*D] bf16 = 25.6MB
  float*    agg  = (float*)((char*)d_out + (size_t)NVD * 2);          // [NE*D] f32
  float*    wsum = (float*)((char*)d_out + (size_t)NVD * 2 + (size_t)NE * D * 4);

  hipMemsetAsync(zstart, 0, zbytes, stream);

  // U1: wprep1 + Bresenham{vconv, count_e+count_v}
  int cb = cdiv(NI, 256);
  int vb = cdiv(NVD, 8192);
  k_u1<<<128 + vb + cb, 256, 0, stream>>>(W1, Wve, b1, bve, Wcf, bc,
                                          vfeat, vbf, NVD,
                                          node_idx, hedge_idx, NI,
                                          cnt_e_pad, cnt_v_pad, rank_e, rank_v,
                                          vb, cb);

  // fused scans (e + v); final includes inline bsum scan (nbe,nbv <= 256)
  int nbe = cdiv(NE, 1024), nbv = cdiv(NV, 1024);
  k_scan_partial2<<<nbe + nbv, 256, 0, stream>>>(cnt_e_pad, NE, bsum_e,
                                                 cnt_v_pad, NV, bsum_v, nbe);
  k_scan_final2<<<nbe + nbv, 256, 0, stream>>>(cnt_e_pad, NE, bsum_e, off_e, cnt_e,
                                               cnt_v_pad, NV, bsum_v, off_v, cnt_v,
                                               nbe, nbv);

  // U2: wprep2 (Wcc, bvec1) + fill_e (plain stores)
  k_u2<<<128 + cb, 256, 0, stream>>>(Wev, Wcf, bc, Wcc, bvec1,
                                     node_idx, hedge_idx, rank_e, NI,
                                     off_e, elist_v);

  // U3: Bresenham{scatter1 -> agg/wsum, fill_v (plain stores)}
  int sb = cdiv(NE, 16);
  int u3_total = sb + cb;
  k_u3<<<u3_total, 256, 0, stream>>>(vbf, off_e, cnt_e, elist_v,
                                     v_reg_weight, e_reg_sum,
                                     agg, wsum, NE, sb, u3_total,
                                     node_idx, hedge_idx, rank_v, NI,
                                     off_v, vlist_e);

  // Wh_e = agg @ Wcc.T + wsum*bvec1 + bev  (bf16 out)
  k_gemm_rs<<<cdiv(NE, 64), 256, 0, stream>>>(agg, Wcc, wsum, bvec1, bev, Wh_e, NE);

  // d_out[v] = (1/vrs[v]) * sum erw[e]*Wh_e[e]
  k_scatter2<<<cdiv(NV, 16), 256, 0, stream>>>(Wh_e, off_v, cnt_v, vlist_e,
                                               e_reg_weight, v_reg_sum,
                                               (float*)d_out, NV);
}